// Round 1
// baseline (107.850 us; speedup 1.0000x reference)
//
#include <hip/hip_runtime.h>

#define L_COLS 2048

// ---------------------------------------------------------------------------
// Kernel 0: compute slice bounds from ppm on-device (robust to linspace fp).
// Python: mn = min(where(ppm <= hi)), mx = max(where(ppm >= lo)); slice [mn:mx)
// windows: gaba(2.8,3.2), glx_shape(3.6,3.9), glx_range(3.55,3.95)
// ---------------------------------------------------------------------------
__global__ void bounds_kernel(const float* __restrict__ ppm, int L, int* __restrict__ ob) {
    __shared__ int smn[3], smx[3];
    if (threadIdx.x < 3) { smn[threadIdx.x] = 0x7fffffff; smx[threadIdx.x] = -1; }
    __syncthreads();
    for (int i = threadIdx.x; i < L; i += blockDim.x) {
        float p = ppm[i];
        if (p <= 3.2f)  atomicMin(&smn[0], i);
        if (p >= 2.8f)  atomicMax(&smx[0], i);
        if (p <= 3.9f)  atomicMin(&smn[1], i);
        if (p >= 3.6f)  atomicMax(&smx[1], i);
        if (p <= 3.95f) atomicMin(&smn[2], i);
        if (p >= 3.55f) atomicMax(&smx[2], i);
    }
    __syncthreads();
    if (threadIdx.x < 3) {
        ob[2 * threadIdx.x]     = smn[threadIdx.x];   // start (inclusive)
        ob[2 * threadIdx.x + 1] = smx[threadIdx.x];   // stop  (exclusive, == mx)
    }
}

__device__ __forceinline__ float wave_red(float v) {
#pragma unroll
    for (int m = 32; m >= 1; m >>= 1) v += __shfl_xor(v, m, 64);
    return v;
}

// ---------------------------------------------------------------------------
// Kernel 1: one wave per row; single pass computes all 5 loss components.
// Pearson is affine-invariant -> norm01 can be skipped exactly.
// acc[0]=sum(0.6*gaba_r+0.4*glx_r), acc[1]=sum|d| gaba, acc[2]=sum|d| glx_range,
// acc[3]=sum|d| global
// ---------------------------------------------------------------------------
__global__ __launch_bounds__(256) void loss_main(const float* __restrict__ x,
                                                 const float* __restrict__ y,
                                                 const int* __restrict__ ob,
                                                 float* __restrict__ acc) {
    const int lane = threadIdx.x & 63;
    const int wv   = threadIdx.x >> 6;
    const long row = (long)blockIdx.x * 4 + wv;

    const int g_lo = ob[0], g_hi = ob[1];
    const int s_lo = ob[2], s_hi = ob[3];
    const int r_lo = ob[4], r_hi = ob[5];

    const float4* __restrict__ x4 = (const float4*)(x + row * L_COLS);
    const float4* __restrict__ y4 = (const float4*)(y + row * L_COLS);

    float gl = 0.f;
    float a_sx = 0, a_sy = 0, a_xy = 0, a_xx = 0, a_yy = 0, a_mae = 0;
    float b_sx = 0, b_sy = 0, b_xy = 0, b_xx = 0, b_yy = 0;
    float r_mae = 0;

#pragma unroll
    for (int k = 0; k < L_COLS / 256; ++k) {
        const int j = k * 64 + lane;          // float4 index within row
        const float4 xv = x4[j];
        const float4 yv = y4[j];
        const float xs[4] = {xv.x, xv.y, xv.z, xv.w};
        const float ys[4] = {yv.x, yv.y, yv.z, yv.w};
#pragma unroll
        for (int e = 0; e < 4; ++e) {
            const int c = 4 * j + e;
            const float xe = xs[e], ye = ys[e];
            const float d = fabsf(xe - ye);
            gl += d;
            if (c >= g_lo && c < g_hi) {
                a_sx += xe; a_sy += ye; a_xy += xe * ye;
                a_xx += xe * xe; a_yy += ye * ye; a_mae += d;
            }
            if (c >= s_lo && c < s_hi) {
                b_sx += xe; b_sy += ye; b_xy += xe * ye;
                b_xx += xe * xe; b_yy += ye * ye;
            }
            if (c >= r_lo && c < r_hi) r_mae += d;
        }
    }

    gl    = wave_red(gl);
    a_sx  = wave_red(a_sx);  a_sy = wave_red(a_sy);
    a_xy  = wave_red(a_xy);  a_xx = wave_red(a_xx);  a_yy = wave_red(a_yy);
    a_mae = wave_red(a_mae);
    b_sx  = wave_red(b_sx);  b_sy = wave_red(b_sy);
    b_xy  = wave_red(b_xy);  b_xx = wave_red(b_xx);  b_yy = wave_red(b_yy);
    r_mae = wave_red(r_mae);

    __shared__ float part[4][4];
    if (lane == 0) {
        const float ng = (float)(g_hi - g_lo);
        const float ns = (float)(s_hi - s_lo);
        const float covA = a_xy - a_sx * a_sy / ng;
        const float vAx  = a_xx - a_sx * a_sx / ng;
        const float vAy  = a_yy - a_sy * a_sy / ng;
        const float scoreA = covA * rsqrtf(vAx * vAy);
        const float covB = b_xy - b_sx * b_sy / ns;
        const float vBx  = b_xx - b_sx * b_sx / ns;
        const float vBy  = b_yy - b_sy * b_sy / ns;
        const float scoreB = covB * rsqrtf(vBx * vBy);
        part[wv][0] = 0.6f * scoreA + 0.4f * scoreB;
        part[wv][1] = a_mae;
        part[wv][2] = r_mae;
        part[wv][3] = gl;
    }
    __syncthreads();
    if (threadIdx.x < 4) {
        const float s = part[0][threadIdx.x] + part[1][threadIdx.x] +
                        part[2][threadIdx.x] + part[3][threadIdx.x];
        atomicAdd(&acc[threadIdx.x], s);
    }
}

// ---------------------------------------------------------------------------
// Kernel 2: combine partial sums into the scalar loss.
// ---------------------------------------------------------------------------
__global__ void finalize_kernel(const float* __restrict__ acc, const int* __restrict__ ob,
                                int Brows, float* __restrict__ out) {
    const float ng = (float)(ob[1] - ob[0]);
    const float nr = (float)(ob[5] - ob[4]);
    const float Bf = (float)Brows;
    const float shape_loss = 1.f - acc[0] / Bf;
    const float gaba_mae = acc[1] / (Bf * ng);
    const float glx_mae  = acc[2] / (Bf * nr);
    const float glob_mae = acc[3] / (Bf * (float)L_COLS);
    const float range_loss = (gaba_mae * 6.f + glx_mae * 3.f + glob_mae) * 0.1f;
    out[0] = shape_loss + range_loss * 0.5f;
}

extern "C" void kernel_launch(void* const* d_in, const int* in_sizes, int n_in,
                              void* d_out, int out_size, void* d_ws, size_t ws_size,
                              hipStream_t stream) {
    const float* x   = (const float*)d_in[0];
    const float* ppm = (const float*)d_in[1];
    const float* y   = (const float*)d_in[2];
    const int L = in_sizes[1];          // 2048 (matches L_COLS)
    const int Brows = in_sizes[0] / L;  // 8192

    float* acc = (float*)d_ws;                 // 4 floats of accumulators
    int*   ob  = (int*)((char*)d_ws + 64);     // 6 ints of bounds

    hipMemsetAsync(d_ws, 0, 64, stream);
    bounds_kernel<<<1, 256, 0, stream>>>(ppm, L, ob);
    loss_main<<<Brows / 4, 256, 0, stream>>>(x, y, ob, acc);
    finalize_kernel<<<1, 1, 0, stream>>>(acc, ob, Brows, (float*)d_out);
}

// Round 2
// 59.943 us; speedup vs baseline: 1.7992x; 1.7992x over previous
//
#include <hip/hip_runtime.h>

#define L_COLS 2048

typedef float vf4 __attribute__((ext_vector_type(4)));

// ---------------------------------------------------------------------------
// Kernel 0: slice bounds from ppm. One wave, register min/max + shfl reduce.
// Python: mn = min(where(ppm <= hi)), mx = max(where(ppm >= lo)); slice [mn:mx)
// windows: gaba(2.8,3.2), glx_shape(3.6,3.9), glx_range(3.55,3.95)
// ---------------------------------------------------------------------------
__global__ __launch_bounds__(64) void bounds_kernel(const float* __restrict__ ppm,
                                                    int L, int* __restrict__ ob) {
    const int lane = threadIdx.x;
    int mn0 = 0x7fffffff, mn1 = 0x7fffffff, mn2 = 0x7fffffff;
    int mx0 = -1, mx1 = -1, mx2 = -1;
    for (int i = lane; i < L; i += 64) {
        const float p = ppm[i];
        if (p <= 3.2f)  mn0 = min(mn0, i);
        if (p >= 2.8f)  mx0 = max(mx0, i);
        if (p <= 3.9f)  mn1 = min(mn1, i);
        if (p >= 3.6f)  mx1 = max(mx1, i);
        if (p <= 3.95f) mn2 = min(mn2, i);
        if (p >= 3.55f) mx2 = max(mx2, i);
    }
#pragma unroll
    for (int m = 32; m >= 1; m >>= 1) {
        mn0 = min(mn0, __shfl_xor(mn0, m, 64));
        mx0 = max(mx0, __shfl_xor(mx0, m, 64));
        mn1 = min(mn1, __shfl_xor(mn1, m, 64));
        mx1 = max(mx1, __shfl_xor(mx1, m, 64));
        mn2 = min(mn2, __shfl_xor(mn2, m, 64));
        mx2 = max(mx2, __shfl_xor(mx2, m, 64));
    }
    if (lane == 0) {
        ob[0] = mn0; ob[1] = mx0;   // gaba  [mn:mx)
        ob[2] = mn1; ob[3] = mx1;   // glx shape
        ob[4] = mn2; ob[5] = mx2;   // glx range
    }
}

__device__ __forceinline__ float wave_red(float v) {
#pragma unroll
    for (int m = 32; m >= 1; m >>= 1) v += __shfl_xor(v, m, 64);
    return v;
}

// ---------------------------------------------------------------------------
// Kernel 1: one wave per row, single streaming pass.
// Pearson is invariant under norm01 (positive affine) -> use raw moments.
// Chunks that cannot intersect any window take a fast |d|-only path
// (wave-uniform scalar branch).
// acc[0]=Σ(0.6*r_gaba+0.4*r_glx), acc[1]=Σ|d| gaba, acc[2]=Σ|d| glx_range,
// acc[3]=Σ|d| global
// ---------------------------------------------------------------------------
__global__ __launch_bounds__(256) void loss_main(const float* __restrict__ x,
                                                 const float* __restrict__ y,
                                                 const int* __restrict__ ob,
                                                 float* __restrict__ acc) {
    const int lane = threadIdx.x & 63;
    const int wv   = threadIdx.x >> 6;
    const long row = (long)blockIdx.x * 4 + wv;

    const int g_lo = ob[0], g_hi = ob[1];
    const int s_lo = ob[2], s_hi = ob[3];
    const int r_lo = ob[4], r_hi = ob[5];
    const int lo_any = min(min(g_lo, s_lo), r_lo);
    const int hi_any = max(max(g_hi, s_hi), r_hi);

    const vf4* __restrict__ x4 = (const vf4*)(x + row * L_COLS);
    const vf4* __restrict__ y4 = (const vf4*)(y + row * L_COLS);

    float gl = 0.f;
    float a_sx = 0, a_sy = 0, a_xy = 0, a_xx = 0, a_yy = 0, a_mae = 0;
    float b_sx = 0, b_sy = 0, b_xy = 0, b_xx = 0, b_yy = 0;
    float r_mae = 0;

#pragma unroll
    for (int k = 0; k < L_COLS / 256; ++k) {
        const int j = k * 64 + lane;                 // float4 index in row
        const vf4 xv = __builtin_nontemporal_load(&x4[j]);
        const vf4 yv = __builtin_nontemporal_load(&y4[j]);
        const float d0 = fabsf(xv.x - yv.x), d1 = fabsf(xv.y - yv.y);
        const float d2 = fabsf(xv.z - yv.z), d3 = fabsf(xv.w - yv.w);
        gl += (d0 + d1) + (d2 + d3);

        // wave-uniform: can this 256-col chunk touch any window?
        if (k * 256 < hi_any && k * 256 + 256 > lo_any) {
            const float xs[4] = {xv.x, xv.y, xv.z, xv.w};
            const float ys[4] = {yv.x, yv.y, yv.z, yv.w};
            const float ds[4] = {d0, d1, d2, d3};
#pragma unroll
            for (int e = 0; e < 4; ++e) {
                const int c = 4 * j + e;
                const float xe = xs[e], ye = ys[e];
                if (c >= g_lo && c < g_hi) {
                    a_sx += xe; a_sy += ye; a_xy += xe * ye;
                    a_xx += xe * xe; a_yy += ye * ye; a_mae += ds[e];
                }
                if (c >= s_lo && c < s_hi) {
                    b_sx += xe; b_sy += ye; b_xy += xe * ye;
                    b_xx += xe * xe; b_yy += ye * ye;
                }
                if (c >= r_lo && c < r_hi) r_mae += ds[e];
            }
        }
    }

    gl    = wave_red(gl);
    a_sx  = wave_red(a_sx);  a_sy = wave_red(a_sy);
    a_xy  = wave_red(a_xy);  a_xx = wave_red(a_xx);  a_yy = wave_red(a_yy);
    a_mae = wave_red(a_mae);
    b_sx  = wave_red(b_sx);  b_sy = wave_red(b_sy);
    b_xy  = wave_red(b_xy);  b_xx = wave_red(b_xx);  b_yy = wave_red(b_yy);
    r_mae = wave_red(r_mae);

    __shared__ float part[4][4];
    if (lane == 0) {
        const float ng = (float)(g_hi - g_lo);
        const float ns = (float)(s_hi - s_lo);
        const float covA = a_xy - a_sx * a_sy / ng;
        const float vAx  = a_xx - a_sx * a_sx / ng;
        const float vAy  = a_yy - a_sy * a_sy / ng;
        const float scoreA = covA * rsqrtf(vAx * vAy);
        const float covB = b_xy - b_sx * b_sy / ns;
        const float vBx  = b_xx - b_sx * b_sx / ns;
        const float vBy  = b_yy - b_sy * b_sy / ns;
        const float scoreB = covB * rsqrtf(vBx * vBy);
        part[wv][0] = 0.6f * scoreA + 0.4f * scoreB;
        part[wv][1] = a_mae;
        part[wv][2] = r_mae;
        part[wv][3] = gl;
    }
    __syncthreads();
    if (threadIdx.x < 4) {
        const float s = part[0][threadIdx.x] + part[1][threadIdx.x] +
                        part[2][threadIdx.x] + part[3][threadIdx.x];
        atomicAdd(&acc[threadIdx.x], s);
    }
}

// ---------------------------------------------------------------------------
// Kernel 2: combine partial sums into the scalar loss.
// ---------------------------------------------------------------------------
__global__ void finalize_kernel(const float* __restrict__ acc, const int* __restrict__ ob,
                                int Brows, float* __restrict__ out) {
    const float ng = (float)(ob[1] - ob[0]);
    const float nr = (float)(ob[5] - ob[4]);
    const float Bf = (float)Brows;
    const float shape_loss = 1.f - acc[0] / Bf;
    const float gaba_mae = acc[1] / (Bf * ng);
    const float glx_mae  = acc[2] / (Bf * nr);
    const float glob_mae = acc[3] / (Bf * (float)L_COLS);
    const float range_loss = (gaba_mae * 6.f + glx_mae * 3.f + glob_mae) * 0.1f;
    out[0] = shape_loss + range_loss * 0.5f;
}

extern "C" void kernel_launch(void* const* d_in, const int* in_sizes, int n_in,
                              void* d_out, int out_size, void* d_ws, size_t ws_size,
                              hipStream_t stream) {
    const float* x   = (const float*)d_in[0];
    const float* ppm = (const float*)d_in[1];
    const float* y   = (const float*)d_in[2];
    const int L = in_sizes[1];          // 2048 (== L_COLS)
    const int Brows = in_sizes[0] / L;  // 8192

    float* acc = (float*)d_ws;                 // 4 floats of accumulators
    int*   ob  = (int*)((char*)d_ws + 64);     // 6 ints of bounds

    hipMemsetAsync(d_ws, 0, 64, stream);
    bounds_kernel<<<1, 64, 0, stream>>>(ppm, L, ob);
    loss_main<<<Brows / 4, 256, 0, stream>>>(x, y, ob, acc);
    finalize_kernel<<<1, 1, 0, stream>>>(acc, ob, Brows, (float*)d_out);
}

// Round 3
// 51.473 us; speedup vs baseline: 2.0953x; 1.1645x over previous
//
#include <hip/hip_runtime.h>

#define L_COLS 2048

typedef float vf4 __attribute__((ext_vector_type(4)));

__device__ __forceinline__ float wave_red(float v) {
#pragma unroll
    for (int m = 32; m >= 1; m >>= 1) v += __shfl_xor(v, m, 64);
    return v;
}

struct Bounds { int g_lo, g_hi, s_lo, s_hi, r_lo, r_hi; };

// Wave-parallel slice-bound scan over ppm (8 KB, L2/L3-hot after first touch).
// Python semantics: start = min(where(ppm <= hi)), stop = max(where(ppm >= lo)),
// slice [start:stop). Windows: gaba(2.8,3.2), glx_shape(3.6,3.9), glx_range(3.55,3.95).
__device__ __forceinline__ Bounds compute_bounds(const float* __restrict__ ppm, int lane) {
    int mn0 = 0x7fffffff, mn1 = 0x7fffffff, mn2 = 0x7fffffff;
    int mx0 = -1, mx1 = -1, mx2 = -1;
    const vf4* __restrict__ p4 = (const vf4*)ppm;
#pragma unroll
    for (int k = 0; k < L_COLS / 256; ++k) {
        const int j = k * 64 + lane;
        const vf4 pv = p4[j];
        const float ps[4] = {pv.x, pv.y, pv.z, pv.w};
#pragma unroll
        for (int e = 0; e < 4; ++e) {
            const int c = 4 * j + e;
            const float p = ps[e];
            if (p <= 3.2f)  mn0 = min(mn0, c);
            if (p >= 2.8f)  mx0 = max(mx0, c);
            if (p <= 3.9f)  mn1 = min(mn1, c);
            if (p >= 3.6f)  mx1 = max(mx1, c);
            if (p <= 3.95f) mn2 = min(mn2, c);
            if (p >= 3.55f) mx2 = max(mx2, c);
        }
    }
#pragma unroll
    for (int m = 32; m >= 1; m >>= 1) {
        mn0 = min(mn0, __shfl_xor(mn0, m, 64));
        mx0 = max(mx0, __shfl_xor(mx0, m, 64));
        mn1 = min(mn1, __shfl_xor(mn1, m, 64));
        mx1 = max(mx1, __shfl_xor(mx1, m, 64));
        mn2 = min(mn2, __shfl_xor(mn2, m, 64));
        mx2 = max(mx2, __shfl_xor(mx2, m, 64));
    }
    Bounds b = {mn0, mx0, mn1, mx1, mn2, mx2};
    return b;
}

// ---------------------------------------------------------------------------
// One wave per row, single streaming pass (plain loads -> L3 retains lines
// across graph replays; the 134 MB working set fits in 256 MiB Infinity Cache).
// Pearson is invariant under norm01 (positive affine) -> raw-moment form.
// acc[0]=Σ(0.6*r_gaba+0.4*r_glx), acc[1]=Σ|d| gaba, acc[2]=Σ|d| glx_range,
// acc[3]=Σ|d| global
// ---------------------------------------------------------------------------
__global__ __launch_bounds__(256) void loss_main(const float* __restrict__ x,
                                                 const float* __restrict__ y,
                                                 const float* __restrict__ ppm,
                                                 float* __restrict__ acc) {
    const int lane = threadIdx.x & 63;
    const int wv   = threadIdx.x >> 6;
    const long row = (long)blockIdx.x * 4 + wv;

    const Bounds b = compute_bounds(ppm, lane);
    const int lo_any = min(min(b.g_lo, b.s_lo), b.r_lo);
    const int hi_any = max(max(b.g_hi, b.s_hi), b.r_hi);

    const vf4* __restrict__ x4 = (const vf4*)(x + row * L_COLS);
    const vf4* __restrict__ y4 = (const vf4*)(y + row * L_COLS);

    float gl = 0.f;
    float a_sx = 0, a_sy = 0, a_xy = 0, a_xx = 0, a_yy = 0, a_mae = 0;
    float b_sx = 0, b_sy = 0, b_xy = 0, b_xx = 0, b_yy = 0;
    float r_mae = 0;

#pragma unroll
    for (int k = 0; k < L_COLS / 256; ++k) {
        const int j = k * 64 + lane;                 // float4 index in row
        const vf4 xv = x4[j];
        const vf4 yv = y4[j];
        const float d0 = fabsf(xv.x - yv.x), d1 = fabsf(xv.y - yv.y);
        const float d2 = fabsf(xv.z - yv.z), d3 = fabsf(xv.w - yv.w);
        gl += (d0 + d1) + (d2 + d3);

        // wave-uniform: can this 256-col chunk touch any window?
        if (k * 256 < hi_any && k * 256 + 256 > lo_any) {
            const float xs[4] = {xv.x, xv.y, xv.z, xv.w};
            const float ys[4] = {yv.x, yv.y, yv.z, yv.w};
            const float ds[4] = {d0, d1, d2, d3};
#pragma unroll
            for (int e = 0; e < 4; ++e) {
                const int c = 4 * j + e;
                const float xe = xs[e], ye = ys[e];
                if (c >= b.g_lo && c < b.g_hi) {
                    a_sx += xe; a_sy += ye; a_xy += xe * ye;
                    a_xx += xe * xe; a_yy += ye * ye; a_mae += ds[e];
                }
                if (c >= b.s_lo && c < b.s_hi) {
                    b_sx += xe; b_sy += ye; b_xy += xe * ye;
                    b_xx += xe * xe; b_yy += ye * ye;
                }
                if (c >= b.r_lo && c < b.r_hi) r_mae += ds[e];
            }
        }
    }

    gl    = wave_red(gl);
    a_sx  = wave_red(a_sx);  a_sy = wave_red(a_sy);
    a_xy  = wave_red(a_xy);  a_xx = wave_red(a_xx);  a_yy = wave_red(a_yy);
    a_mae = wave_red(a_mae);
    b_sx  = wave_red(b_sx);  b_sy = wave_red(b_sy);
    b_xy  = wave_red(b_xy);  b_xx = wave_red(b_xx);  b_yy = wave_red(b_yy);
    r_mae = wave_red(r_mae);

    __shared__ float part[4][4];
    if (lane == 0) {
        const float ng = (float)(b.g_hi - b.g_lo);
        const float ns = (float)(b.s_hi - b.s_lo);
        const float covA = a_xy - a_sx * a_sy / ng;
        const float vAx  = a_xx - a_sx * a_sx / ng;
        const float vAy  = a_yy - a_sy * a_sy / ng;
        const float scoreA = covA * rsqrtf(vAx * vAy);
        const float covB = b_xy - b_sx * b_sy / ns;
        const float vBx  = b_xx - b_sx * b_sx / ns;
        const float vBy  = b_yy - b_sy * b_sy / ns;
        const float scoreB = covB * rsqrtf(vBx * vBy);
        part[wv][0] = 0.6f * scoreA + 0.4f * scoreB;
        part[wv][1] = a_mae;
        part[wv][2] = r_mae;
        part[wv][3] = gl;
    }
    __syncthreads();
    if (threadIdx.x < 4) {
        const float s = part[0][threadIdx.x] + part[1][threadIdx.x] +
                        part[2][threadIdx.x] + part[3][threadIdx.x];
        atomicAdd(&acc[threadIdx.x], s);
    }
}

// ---------------------------------------------------------------------------
// Finalize: one wave recomputes bounds (for window lengths) and emits the loss.
// ---------------------------------------------------------------------------
__global__ __launch_bounds__(64) void finalize_kernel(const float* __restrict__ acc,
                                                      const float* __restrict__ ppm,
                                                      int Brows, float* __restrict__ out) {
    const Bounds b = compute_bounds(ppm, threadIdx.x);
    if (threadIdx.x == 0) {
        const float ng = (float)(b.g_hi - b.g_lo);
        const float nr = (float)(b.r_hi - b.r_lo);
        const float Bf = (float)Brows;
        const float shape_loss = 1.f - acc[0] / Bf;
        const float gaba_mae = acc[1] / (Bf * ng);
        const float glx_mae  = acc[2] / (Bf * nr);
        const float glob_mae = acc[3] / (Bf * (float)L_COLS);
        const float range_loss = (gaba_mae * 6.f + glx_mae * 3.f + glob_mae) * 0.1f;
        out[0] = shape_loss + range_loss * 0.5f;
    }
}

extern "C" void kernel_launch(void* const* d_in, const int* in_sizes, int n_in,
                              void* d_out, int out_size, void* d_ws, size_t ws_size,
                              hipStream_t stream) {
    const float* x   = (const float*)d_in[0];
    const float* ppm = (const float*)d_in[1];
    const float* y   = (const float*)d_in[2];
    const int L = in_sizes[1];          // 2048 (== L_COLS)
    const int Brows = in_sizes[0] / L;  // 8192

    float* acc = (float*)d_ws;          // 4 floats of accumulators

    hipMemsetAsync(d_ws, 0, 16, stream);
    loss_main<<<Brows / 4, 256, 0, stream>>>(x, y, ppm, acc);
    finalize_kernel<<<1, 64, 0, stream>>>(acc, ppm, Brows, (float*)d_out);
}

// Round 4
// 46.319 us; speedup vs baseline: 2.3284x; 1.1113x over previous
//
#include <hip/hip_runtime.h>

#define L_COLS 2048

typedef float vf4 __attribute__((ext_vector_type(4)));

__device__ __forceinline__ float wave_red(float v) {
#pragma unroll
    for (int m = 32; m >= 1; m >>= 1) v += __shfl_xor(v, m, 64);
    return v;
}

// ---------------------------------------------------------------------------
// Init: one wave computes slice bounds from ppm (register min/max + shfl) and
// zeroes the accumulators. Replaces both the memset and the bounds kernel.
// Python: start = min(where(ppm <= hi)), stop = max(where(ppm >= lo)); [start:stop)
// windows: gaba(2.8,3.2), glx_shape(3.6,3.9), glx_range(3.55,3.95)
// ---------------------------------------------------------------------------
__global__ __launch_bounds__(64) void init_kernel(const float* __restrict__ ppm,
                                                  float* __restrict__ acc,
                                                  int* __restrict__ ob) {
    const int lane = threadIdx.x;
    if (lane < 4) acc[lane] = 0.f;

    int mn0 = 0x7fffffff, mn1 = 0x7fffffff, mn2 = 0x7fffffff;
    int mx0 = -1, mx1 = -1, mx2 = -1;
    const vf4* __restrict__ p4 = (const vf4*)ppm;
#pragma unroll
    for (int k = 0; k < L_COLS / 256; ++k) {
        const int j = k * 64 + lane;
        const vf4 pv = p4[j];
        const float ps[4] = {pv.x, pv.y, pv.z, pv.w};
#pragma unroll
        for (int e = 0; e < 4; ++e) {
            const int c = 4 * j + e;
            const float p = ps[e];
            if (p <= 3.2f)  mn0 = min(mn0, c);
            if (p >= 2.8f)  mx0 = max(mx0, c);
            if (p <= 3.9f)  mn1 = min(mn1, c);
            if (p >= 3.6f)  mx1 = max(mx1, c);
            if (p <= 3.95f) mn2 = min(mn2, c);
            if (p >= 3.55f) mx2 = max(mx2, c);
        }
    }
#pragma unroll
    for (int m = 32; m >= 1; m >>= 1) {
        mn0 = min(mn0, __shfl_xor(mn0, m, 64));
        mx0 = max(mx0, __shfl_xor(mx0, m, 64));
        mn1 = min(mn1, __shfl_xor(mn1, m, 64));
        mx1 = max(mx1, __shfl_xor(mx1, m, 64));
        mn2 = min(mn2, __shfl_xor(mn2, m, 64));
        mx2 = max(mx2, __shfl_xor(mx2, m, 64));
    }
    if (lane == 0) {
        ob[0] = mn0; ob[1] = mx0;   // gaba  [lo:hi)
        ob[2] = mn1; ob[3] = mx1;   // glx shape
        ob[4] = mn2; ob[5] = mx2;   // glx range
    }
}

// ---------------------------------------------------------------------------
// One wave per row. Stage the FULL row pair in registers first (16 outstanding
// global_load_dwordx4 -> 16 KB in flight per wave; Little's-law fix for the
// latency-bound profile), then compute. Pearson via raw moments (norm01 is a
// positive affine map -> correlation invariant).
// acc[0]=Σ(0.6*r_gaba+0.4*r_glx), acc[1]=Σ|d| gaba, acc[2]=Σ|d| glx_range,
// acc[3]=Σ|d| global
// ---------------------------------------------------------------------------
__global__ __launch_bounds__(256, 2) void loss_main(const float* __restrict__ x,
                                                    const float* __restrict__ y,
                                                    const int* __restrict__ ob,
                                                    float* __restrict__ acc) {
    const int lane = threadIdx.x & 63;
    const int wv   = threadIdx.x >> 6;
    const long row = (long)blockIdx.x * 4 + wv;

    const int g_lo = ob[0], g_hi = ob[1];
    const int s_lo = ob[2], s_hi = ob[3];
    const int r_lo = ob[4], r_hi = ob[5];
    const int lo_any = min(min(g_lo, s_lo), r_lo);
    const int hi_any = max(max(g_hi, s_hi), r_hi);

    const vf4* __restrict__ x4 = (const vf4*)(x + row * L_COLS);
    const vf4* __restrict__ y4 = (const vf4*)(y + row * L_COLS);

    // ---- stage full row pair in registers: all 16 loads issued back-to-back
    vf4 xr[8], yr[8];
#pragma unroll
    for (int k = 0; k < 8; ++k) xr[k] = x4[k * 64 + lane];
#pragma unroll
    for (int k = 0; k < 8; ++k) yr[k] = y4[k * 64 + lane];

    float gl = 0.f;
    float a_sx = 0, a_sy = 0, a_xy = 0, a_xx = 0, a_yy = 0, a_mae = 0;
    float b_sx = 0, b_sy = 0, b_xy = 0, b_xx = 0, b_yy = 0;
    float r_mae = 0;

#pragma unroll
    for (int k = 0; k < 8; ++k) {
        const vf4 xv = xr[k];
        const vf4 yv = yr[k];
        const float d0 = fabsf(xv.x - yv.x), d1 = fabsf(xv.y - yv.y);
        const float d2 = fabsf(xv.z - yv.z), d3 = fabsf(xv.w - yv.w);
        gl += (d0 + d1) + (d2 + d3);

        // wave-uniform: can this 256-col chunk touch any window?
        if (k * 256 < hi_any && k * 256 + 256 > lo_any) {
            const float xs[4] = {xv.x, xv.y, xv.z, xv.w};
            const float ys[4] = {yv.x, yv.y, yv.z, yv.w};
            const float ds[4] = {d0, d1, d2, d3};
#pragma unroll
            for (int e = 0; e < 4; ++e) {
                const int c = k * 256 + 4 * lane + e;
                const float xe = xs[e], ye = ys[e];
                if (c >= g_lo && c < g_hi) {
                    a_sx += xe; a_sy += ye; a_xy += xe * ye;
                    a_xx += xe * xe; a_yy += ye * ye; a_mae += ds[e];
                }
                if (c >= s_lo && c < s_hi) {
                    b_sx += xe; b_sy += ye; b_xy += xe * ye;
                    b_xx += xe * xe; b_yy += ye * ye;
                }
                if (c >= r_lo && c < r_hi) r_mae += ds[e];
            }
        }
    }

    gl    = wave_red(gl);
    a_sx  = wave_red(a_sx);  a_sy = wave_red(a_sy);
    a_xy  = wave_red(a_xy);  a_xx = wave_red(a_xx);  a_yy = wave_red(a_yy);
    a_mae = wave_red(a_mae);
    b_sx  = wave_red(b_sx);  b_sy = wave_red(b_sy);
    b_xy  = wave_red(b_xy);  b_xx = wave_red(b_xx);  b_yy = wave_red(b_yy);
    r_mae = wave_red(r_mae);

    __shared__ float part[4][4];
    if (lane == 0) {
        const float ng = (float)(g_hi - g_lo);
        const float ns = (float)(s_hi - s_lo);
        const float covA = a_xy - a_sx * a_sy / ng;
        const float vAx  = a_xx - a_sx * a_sx / ng;
        const float vAy  = a_yy - a_sy * a_sy / ng;
        const float scoreA = covA * rsqrtf(vAx * vAy);
        const float covB = b_xy - b_sx * b_sy / ns;
        const float vBx  = b_xx - b_sx * b_sx / ns;
        const float vBy  = b_yy - b_sy * b_sy / ns;
        const float scoreB = covB * rsqrtf(vBx * vBy);
        part[wv][0] = 0.6f * scoreA + 0.4f * scoreB;
        part[wv][1] = a_mae;
        part[wv][2] = r_mae;
        part[wv][3] = gl;
    }
    __syncthreads();
    if (threadIdx.x < 4) {
        const float s = part[0][threadIdx.x] + part[1][threadIdx.x] +
                        part[2][threadIdx.x] + part[3][threadIdx.x];
        atomicAdd(&acc[threadIdx.x], s);
    }
}

// ---------------------------------------------------------------------------
// Finalize: single thread combines partial sums into the scalar loss.
// ---------------------------------------------------------------------------
__global__ void finalize_kernel(const float* __restrict__ acc, const int* __restrict__ ob,
                                int Brows, float* __restrict__ out) {
    const float ng = (float)(ob[1] - ob[0]);
    const float nr = (float)(ob[5] - ob[4]);
    const float Bf = (float)Brows;
    const float shape_loss = 1.f - acc[0] / Bf;
    const float gaba_mae = acc[1] / (Bf * ng);
    const float glx_mae  = acc[2] / (Bf * nr);
    const float glob_mae = acc[3] / (Bf * (float)L_COLS);
    const float range_loss = (gaba_mae * 6.f + glx_mae * 3.f + glob_mae) * 0.1f;
    out[0] = shape_loss + range_loss * 0.5f;
}

extern "C" void kernel_launch(void* const* d_in, const int* in_sizes, int n_in,
                              void* d_out, int out_size, void* d_ws, size_t ws_size,
                              hipStream_t stream) {
    const float* x   = (const float*)d_in[0];
    const float* ppm = (const float*)d_in[1];
    const float* y   = (const float*)d_in[2];
    const int L = in_sizes[1];          // 2048 (== L_COLS)
    const int Brows = in_sizes[0] / L;  // 8192

    float* acc = (float*)d_ws;                 // 4 floats of accumulators
    int*   ob  = (int*)((char*)d_ws + 64);     // 6 ints of bounds

    init_kernel<<<1, 64, 0, stream>>>(ppm, acc, ob);
    loss_main<<<Brows / 4, 256, 0, stream>>>(x, y, ob, acc);
    finalize_kernel<<<1, 1, 0, stream>>>(acc, ob, Brows, (float*)d_out);
}